// Round 1
// baseline (642.626 us; speedup 1.0000x reference)
//
#include <hip/hip_runtime.h>
#include <math.h>

#define NP 16384
#define NR 8192

// ---------------- transpose rgb_features (128, NR) -> rgbT (NR+1, 128); zero shadow row
__global__ __launch_bounds__(256) void k_transpose(const float* __restrict__ rf,
                                                   float* __restrict__ rgbT) {
  __shared__ float tile[128][65];
  int t = threadIdx.x;
  int r0 = blockIdx.x * 64;
  for (int e = 0; e < 32; ++e) {
    int idx = t + e * 256;            // 0..8191 -> 128 c x 64 r
    int c = idx >> 6, rl = idx & 63;
    tile[c][rl] = rf[c * NR + r0 + rl];
  }
  __syncthreads();
  for (int e = 0; e < 32; ++e) {
    int idx = t + e * 256;            // 64 r x 128 c
    int rl = idx >> 7, c = idx & 127;
    rgbT[(r0 + rl) * 128 + c] = tile[c][rl];
  }
  if (blockIdx.x == 0 && t < 128) rgbT[NR * 128 + t] = 0.f;
}

// ---------------- three_nn: per pcd point, 3 nearest rgb points + radius mask
__global__ __launch_bounds__(256) void k_three_nn(const float* __restrict__ pxyz,
                                                  const float* __restrict__ rxyz,
                                                  int* __restrict__ nb) {
  __shared__ float4 pts[2048];          // 4 waves x 512 staged points
  __shared__ float msd[4][3][64];
  __shared__ int   mid[4][3][64];
  int t = threadIdx.x;
  int lane = t & 63, w = t >> 6;
  int n = blockIdx.x * 64 + lane;
  float px = pxyz[n * 3], py = pxyz[n * 3 + 1], pz = pxyz[n * 3 + 2];
  float s0 = 3.4e38f, s1 = 3.4e38f, s2 = 3.4e38f;
  int i0 = 0, i1 = 0, i2 = 0;
  for (int p = 0; p < 4; ++p) {
    // stage: wave ww's sub-chunk p lives at pts[ww*512 ..]
    for (int e = 0; e < 8; ++e) {
      int gi = t + e * 256;             // 0..2047
      int ww = gi >> 9, loc = gi & 511;
      int q = ww * 2048 + p * 512 + loc;
      pts[gi] = make_float4(rxyz[q * 3], rxyz[q * 3 + 1], rxyz[q * 3 + 2], 0.f);
    }
    __syncthreads();
    int base = w * 512;
    int gbase = w * 2048 + p * 512;
    for (int loc = 0; loc < 512; ++loc) {
      float4 r = pts[base + loc];
      float dx = px - r.x, dy = py - r.y, dz = pz - r.z;
      float d2 = dx * dx + dy * dy + dz * dz;
      if (d2 < s2) {                    // strict < : ties keep earlier index (top_k semantics)
        int i = gbase + loc;
        if (d2 < s1) {
          s2 = s1; i2 = i1;
          if (d2 < s0) { s1 = s0; i1 = i0; s0 = d2; i0 = i; }
          else         { s1 = d2; i1 = i; }
        } else { s2 = d2; i2 = i; }
      }
    }
    __syncthreads();
  }
  msd[w][0][lane] = s0; msd[w][1][lane] = s1; msd[w][2][lane] = s2;
  mid[w][0][lane] = i0; mid[w][1][lane] = i1; mid[w][2][lane] = i2;
  __syncthreads();
  if (t < 64) {
    s0 = msd[0][0][t]; s1 = msd[0][1][t]; s2 = msd[0][2][t];
    i0 = mid[0][0][t]; i1 = mid[0][1][t]; i2 = mid[0][2][t];
    for (int ww = 1; ww < 4; ++ww) {    // merge in ascending-idx order (tie-break correct)
      for (int q = 0; q < 3; ++q) {
        float d2 = msd[ww][q][t]; int i = mid[ww][q][t];
        if (d2 < s2) {
          if (d2 < s1) {
            s2 = s1; i2 = i1;
            if (d2 < s0) { s1 = s0; i1 = i0; s0 = d2; i0 = i; }
            else         { s1 = d2; i1 = i; }
          } else { s2 = d2; i2 = i; }
        }
      }
    }
    const float R2 = 0.075f * 0.075f;   // dist > R  <=>  d2 > R^2
    int nn = blockIdx.x * 64 + t;
    nb[nn * 3 + 0] = (s0 > R2) ? NR : i0;
    nb[nn * 3 + 1] = (s1 > R2) ? NR : i1;
    nb[nn * 3 + 2] = (s2 > R2) ? NR : i2;
  }
}

// ---------------- gather neighbor features -> x_cat (384, NP) channel-major
__global__ __launch_bounds__(192) void k_gather(const float* __restrict__ rgbT,
                                                const int* __restrict__ nb,
                                                float* __restrict__ xcat) {
  int t = threadIdx.x;                  // 3 waves: wave j handles neighbor j
  int j = t >> 6, lane = t & 63;
  int n = blockIdx.x * 64 + lane;
  int idx = nb[n * 3 + j];
  const float4* row = (const float4*)(rgbT + (size_t)idx * 128);
  for (int c4 = 0; c4 < 32; ++c4) {
    float4 v = row[c4];
    int cb = j * 128 + c4 * 4;
    xcat[(size_t)(cb + 0) * NP + n] = v.x;
    xcat[(size_t)(cb + 1) * NP + n] = v.y;
    xcat[(size_t)(cb + 2) * NP + n] = v.z;
    xcat[(size_t)(cb + 3) * NP + n] = v.w;
  }
}

// ---------------- max over 3 neighbors -> x2 rows 128..255
__global__ __launch_bounds__(256) void k_max3(const float* __restrict__ xcat,
                                              float* __restrict__ x2) {
  int idx = blockIdx.x * 256 + threadIdx.x;   // 128*NP threads
  int c = idx >> 14, n = idx & 16383;
  float a = xcat[(size_t)c * NP + n];
  float b = xcat[(size_t)(128 + c) * NP + n];
  float d = xcat[(size_t)(256 + c) * NP + n];
  x2[(size_t)(128 + c) * NP + n] = fmaxf(a, fmaxf(b, d));
}

// ---------------- generic fp32 GEMM: Y[o,n] = act(bn(sum_c W[o,c] X[c,n] + bias[o]))
// 128x128 tile, 8x8 micro, K-chunk 16
template <bool BN, bool RELU>
__global__ __launch_bounds__(256) void k_gemm(const float* __restrict__ W,
                                              const float* __restrict__ bias,
                                              const float* __restrict__ bn,
                                              const float* __restrict__ X,
                                              float* __restrict__ Y, int O, int C) {
  __shared__ float Xs[16][128];
  __shared__ float Ws[16][132];         // +4 pad: conflict-free transposed writes
  __shared__ float scs[128], shs[128];
  int t = threadIdx.x;
  int n0 = blockIdx.x * 128, o0 = blockIdx.y * 128;
  if (t < 128) {
    int o = o0 + t;
    float sc = 1.f, sh = 0.f;
    if (o < O) {
      float b = bias[o];
      if (BN) {
        float g = bn[o], be = bn[O + o], m = bn[2 * O + o], v = bn[3 * O + o];
        float inv = g * rsqrtf(v + 1e-5f);
        sc = inv; sh = (b - m) * inv + be;
      } else { sh = b; }
    }
    scs[t] = sc; shs[t] = sh;
  }
  float acc[8][8];
#pragma unroll
  for (int a = 0; a < 8; ++a)
#pragma unroll
    for (int b = 0; b < 8; ++b) acc[a][b] = 0.f;
  int tn = t & 15, tc = t >> 4;
  for (int c0 = 0; c0 < C; c0 += 16) {
    __syncthreads();
#pragma unroll
    for (int e = 0; e < 2; ++e) {       // X tile 16k x 128n
      int idx = t + e * 256;
      int k = idx >> 5, n4 = idx & 31;
      float4 v = *(const float4*)(X + (size_t)(c0 + k) * NP + n0 + n4 * 4);
      *(float4*)&Xs[k][n4 * 4] = v;
    }
#pragma unroll
    for (int e = 0; e < 2; ++e) {       // W tile 128o x 16k, transposed into [k][o]
      int idx = t + e * 256;
      int o = idx >> 2, k4 = (idx & 3) * 4;
      float4 v = make_float4(0.f, 0.f, 0.f, 0.f);
      if (o0 + o < O) v = *(const float4*)(W + (size_t)(o0 + o) * C + c0 + k4);
      Ws[k4 + 0][o] = v.x; Ws[k4 + 1][o] = v.y;
      Ws[k4 + 2][o] = v.z; Ws[k4 + 3][o] = v.w;
    }
    __syncthreads();
#pragma unroll
    for (int k = 0; k < 16; ++k) {
      float xa[8], wa[8];
      *(float4*)&xa[0] = *(const float4*)&Xs[k][tn * 8];
      *(float4*)&xa[4] = *(const float4*)&Xs[k][tn * 8 + 4];
      *(float4*)&wa[0] = *(const float4*)&Ws[k][tc * 8];
      *(float4*)&wa[4] = *(const float4*)&Ws[k][tc * 8 + 4];
#pragma unroll
      for (int a = 0; a < 8; ++a)
#pragma unroll
        for (int b = 0; b < 8; ++b) acc[a][b] = fmaf(wa[a], xa[b], acc[a][b]);
    }
  }
#pragma unroll
  for (int a = 0; a < 8; ++a) {
    int o = o0 + tc * 8 + a;
    if (o < O) {
      float sc = scs[tc * 8 + a], sh = shs[tc * 8 + a];
      float r[8];
#pragma unroll
      for (int b = 0; b < 8; ++b) {
        float v = acc[a][b] * sc + sh;
        if (RELU) v = fmaxf(v, 0.f);
        r[b] = v;
      }
      float* yp = Y + (size_t)o * NP + n0 + tn * 8;
      *(float4*)yp = *(float4*)&r[0];
      *(float4*)(yp + 4) = *(float4*)&r[4];
    }
  }
}

// ---------------- score head: sigmoid(sh2_w . s + b)
__global__ __launch_bounds__(256) void k_score(const float* __restrict__ S,
                                               const float* __restrict__ w,
                                               const float* __restrict__ b,
                                               float* __restrict__ out) {
  int n = blockIdx.x * 256 + threadIdx.x;
  float acc = b[0];
  for (int c = 0; c < 128; ++c) acc = fmaf(w[c], S[(size_t)c * NP + n], acc);
  out[n] = 1.f / (1.f + expf(-acc));
}

// ---------------- L2-normalize fp columns, write transposed (NP, 128)
__global__ __launch_bounds__(256) void k_norm(const float* __restrict__ FP,
                                              float* __restrict__ out) {
  __shared__ float tile[128][65];
  __shared__ float part[4][64];
  __shared__ float inv[64];
  int t = threadIdx.x;
  int n0 = blockIdx.x * 64;
  for (int e = 0; e < 32; ++e) {
    int idx = t + e * 256;
    int c = idx >> 6, j = idx & 63;
    tile[c][j] = FP[(size_t)c * NP + n0 + j];
  }
  __syncthreads();
  int g = t >> 6, j = t & 63;
  float s = 0.f;
  for (int c = g * 32; c < g * 32 + 32; ++c) { float v = tile[c][j]; s = fmaf(v, v, s); }
  part[g][j] = s;
  __syncthreads();
  if (t < 64) {
    float nrm = sqrtf(part[0][t] + part[1][t] + part[2][t] + part[3][t]);
    inv[t] = 1.f / fmaxf(nrm, 1e-12f);
  }
  __syncthreads();
  for (int e = 0; e < 32; ++e) {
    int idx = t + e * 256;
    int jj = idx >> 7, c = idx & 127;
    out[(size_t)(n0 + jj) * 128 + c] = tile[c][jj] * inv[jj];
  }
}

// ---------------- float4 copy
__global__ __launch_bounds__(256) void k_copy4(const float4* __restrict__ src,
                                               float4* __restrict__ dst, int n4) {
  int i = blockIdx.x * 256 + threadIdx.x;
  if (i < n4) dst[i] = src[i];
}

extern "C" void kernel_launch(void* const* d_in, const int* in_sizes, int n_in,
                              void* d_out, int out_size, void* d_ws, size_t ws_size,
                              hipStream_t stream) {
  const float* pcd_xyz = (const float*)d_in[0];
  const float* rgb_xyz = (const float*)d_in[1];
  const float* pcd_f   = (const float*)d_in[2];
  const float* rgb_f   = (const float*)d_in[3];
  const float* cc1_w = (const float*)d_in[4];  const float* cc1_b = (const float*)d_in[5];
  const float* cc_bn = (const float*)d_in[6];
  const float* cc2_w = (const float*)d_in[7];  const float* cc2_b = (const float*)d_in[8];
  const float* co1_w = (const float*)d_in[9];  const float* co1_b = (const float*)d_in[10];
  const float* co_bn = (const float*)d_in[11];
  const float* co2_w = (const float*)d_in[12]; const float* co2_b = (const float*)d_in[13];
  const float* dh1_w = (const float*)d_in[14]; const float* dh1_b = (const float*)d_in[15];
  const float* dh1_bn = (const float*)d_in[16];
  const float* dh2_w = (const float*)d_in[17]; const float* dh2_b = (const float*)d_in[18];
  const float* dh2_bn = (const float*)d_in[19];
  const float* dh3_w = (const float*)d_in[20]; const float* dh3_b = (const float*)d_in[21];
  const float* sh1_w = (const float*)d_in[22]; const float* sh1_b = (const float*)d_in[23];
  const float* sh_bn = (const float*)d_in[24];
  const float* sh2_w = (const float*)d_in[25]; const float* sh2_b = (const float*)d_in[26];

  float* ws = (float*)d_ws;
  float* out = (float*)d_out;

  // workspace layout (floats); ~90.4 MB total with aliasing
  float* rgbT = ws;                                  // 8193*128 = 1,048,704
  int*   nb   = (int*)(ws + 1048704);                // 49,152 ints
  float* bufA = ws + 1097856;                        // 6,291,456 : x_cat; later h3/h4
  float* bufB = ws + 7389312;                        // 6,291,456 : h1; h2; s
  float* x2   = ws + 13680768;                       // 4,194,304
  float* full = ws + 17875072;                       // 2,621,440
  float* fp   = ws + 20496512;                       // 2,097,152
  float* h3 = bufA;
  float* h4 = bufA + 2621440;

  k_transpose<<<128, 256, 0, stream>>>(rgb_f, rgbT);
  k_three_nn<<<256, 256, 0, stream>>>(pcd_xyz, rgb_xyz, nb);
  k_gather<<<256, 192, 0, stream>>>(rgbT, nb, bufA);                 // x_cat
  k_max3<<<8192, 256, 0, stream>>>(bufA, x2);                        // x2 rows 128..255
  k_copy4<<<512, 256, 0, stream>>>((const float4*)pcd_f, (float4*)full, 131072); // full rows 0..31

  k_gemm<true, true><<<dim3(128, 3), 256, 0, stream>>>(cc1_w, cc1_b, cc_bn, bufA, bufB, 384, 384);
  k_gemm<false, false><<<dim3(128, 1), 256, 0, stream>>>(cc2_w, cc2_b, nullptr, bufB, x2, 128, 384);
  k_gemm<true, true><<<dim3(128, 2), 256, 0, stream>>>(co1_w, co1_b, co_bn, x2, bufB, 256, 256);
  k_gemm<false, false><<<dim3(128, 1), 256, 0, stream>>>(co2_w, co2_b, nullptr, bufB, full + 32 * NP, 128, 256);
  k_gemm<true, true><<<dim3(128, 2), 256, 0, stream>>>(dh1_w, dh1_b, dh1_bn, full, h3, 160, 160);
  k_gemm<true, true><<<dim3(128, 2), 256, 0, stream>>>(dh2_w, dh2_b, dh2_bn, h3, h4, 160, 160);
  k_gemm<false, false><<<dim3(128, 1), 256, 0, stream>>>(dh3_w, dh3_b, nullptr, h4, fp, 128, 160);
  k_gemm<true, true><<<dim3(128, 1), 256, 0, stream>>>(sh1_w, sh1_b, sh_bn, fp, bufB, 128, 128);

  k_score<<<64, 256, 0, stream>>>(bufB, sh2_w, sh2_b, out + 49152);
  k_norm<<<256, 256, 0, stream>>>(fp, out + 65536);
  k_copy4<<<48, 256, 0, stream>>>((const float4*)pcd_xyz, (float4*)out, 12288);
}

// Round 2
// 532.096 us; speedup vs baseline: 1.2077x; 1.2077x over previous
//
#include <hip/hip_runtime.h>
#include <math.h>

#define NP 16384
#define NR 8192

// ---------------- transpose rgb_features (128, NR) -> rgbT (NR+1, 128); zero shadow row
__global__ __launch_bounds__(256) void k_transpose(const float* __restrict__ rf,
                                                   float* __restrict__ rgbT) {
  __shared__ float tile[128][65];
  int t = threadIdx.x;
  int r0 = blockIdx.x * 64;
  for (int e = 0; e < 32; ++e) {
    int idx = t + e * 256;            // 0..8191 -> 128 c x 64 r
    int c = idx >> 6, rl = idx & 63;
    tile[c][rl] = rf[c * NR + r0 + rl];
  }
  __syncthreads();
  for (int e = 0; e < 32; ++e) {
    int idx = t + e * 256;            // 64 r x 128 c
    int rl = idx >> 7, c = idx & 127;
    rgbT[(r0 + rl) * 128 + c] = tile[c][rl];
  }
  if (blockIdx.x == 0 && t < 128) rgbT[NR * 128 + t] = 0.f;
}

// ---------------- three_nn partials: grid (256 groups, 8 splits); block = 64 pcd pts,
// 4 waves each scan 256 rgb pts of this split's 1024-point chunk.
__global__ __launch_bounds__(256) void k_nn_part(const float* __restrict__ pxyz,
                                                 const float* __restrict__ rxyz,
                                                 float* __restrict__ pd,
                                                 int* __restrict__ pi) {
  __shared__ float4 pts[1024];          // 16 KB
  __shared__ float msd[4][3][64];
  __shared__ int   mid[4][3][64];
  int t = threadIdx.x;
  int g = blockIdx.x, s = blockIdx.y;
  int lane = t & 63, w = t >> 6;
  int rbase = s * 1024;
#pragma unroll
  for (int e = 0; e < 4; ++e) {
    int q = t + e * 256;
    int ri = (rbase + q) * 3;
    pts[q] = make_float4(rxyz[ri], rxyz[ri + 1], rxyz[ri + 2], 0.f);
  }
  int n = g * 64 + lane;
  float px = pxyz[n * 3], py = pxyz[n * 3 + 1], pz = pxyz[n * 3 + 2];
  __syncthreads();
  float s0 = 3.4e38f, s1 = 3.4e38f, s2 = 3.4e38f;
  int i0 = 0, i1 = 0, i2 = 0;
  int base = w * 256;
#pragma unroll 4
  for (int loc = 0; loc < 256; ++loc) {
    float4 r = pts[base + loc];
    float dx = px - r.x, dy = py - r.y, dz = pz - r.z;
    float d2 = fmaf(dx, dx, fmaf(dy, dy, dz * dz));
    if (d2 < s2) {                      // strict <: ties keep earlier index (top_k semantics)
      int i = rbase + base + loc;
      if (d2 < s1) {
        s2 = s1; i2 = i1;
        if (d2 < s0) { s1 = s0; i1 = i0; s0 = d2; i0 = i; }
        else         { s1 = d2; i1 = i; }
      } else { s2 = d2; i2 = i; }
    }
  }
  msd[w][0][lane] = s0; msd[w][1][lane] = s1; msd[w][2][lane] = s2;
  mid[w][0][lane] = i0; mid[w][1][lane] = i1; mid[w][2][lane] = i2;
  __syncthreads();
  if (t < 64) {
    s0 = msd[0][0][t]; s1 = msd[0][1][t]; s2 = msd[0][2][t];
    i0 = mid[0][0][t]; i1 = mid[0][1][t]; i2 = mid[0][2][t];
    for (int ww = 1; ww < 4; ++ww) {    // ascending-idx order: tie-break correct
      for (int q = 0; q < 3; ++q) {
        float d2 = msd[ww][q][t]; int i = mid[ww][q][t];
        if (d2 < s2) {
          if (d2 < s1) {
            s2 = s1; i2 = i1;
            if (d2 < s0) { s1 = s0; i1 = i0; s0 = d2; i0 = i; }
            else         { s1 = d2; i1 = i; }
          } else { s2 = d2; i2 = i; }
        }
      }
    }
    int off = ((g * 8 + s) * 64 + t) * 3;
    pd[off + 0] = s0; pd[off + 1] = s1; pd[off + 2] = s2;
    pi[off + 0] = i0; pi[off + 1] = i1; pi[off + 2] = i2;
  }
}

// ---------------- merge 8 split-partials per point, radius mask, write neighbors
__global__ __launch_bounds__(256) void k_nn_merge(const float* __restrict__ pd,
                                                  const int* __restrict__ pi,
                                                  int* __restrict__ nb) {
  int n = blockIdx.x * 256 + threadIdx.x;
  int g = n >> 6, l = n & 63;
  float s0 = 3.4e38f, s1 = 3.4e38f, s2 = 3.4e38f;
  int i0 = 0, i1 = 0, i2 = 0;
  for (int s = 0; s < 8; ++s) {         // ascending split order: tie-break correct
    int off = ((g * 8 + s) * 64 + l) * 3;
#pragma unroll
    for (int q = 0; q < 3; ++q) {
      float d2 = pd[off + q]; int i = pi[off + q];
      if (d2 < s2) {
        if (d2 < s1) {
          s2 = s1; i2 = i1;
          if (d2 < s0) { s1 = s0; i1 = i0; s0 = d2; i0 = i; }
          else         { s1 = d2; i1 = i; }
        } else { s2 = d2; i2 = i; }
      }
    }
  }
  const float R2 = 0.075f * 0.075f;     // dist > R  <=>  d2 > R^2
  nb[n * 3 + 0] = (s0 > R2) ? NR : i0;
  nb[n * 3 + 1] = (s1 > R2) ? NR : i1;
  nb[n * 3 + 2] = (s2 > R2) ? NR : i2;
}

// ---------------- gather neighbor features -> x_cat (384, NP) channel-major
__global__ __launch_bounds__(192) void k_gather(const float* __restrict__ rgbT,
                                                const int* __restrict__ nb,
                                                float* __restrict__ xcat) {
  int t = threadIdx.x;                  // 3 waves: wave j handles neighbor j
  int j = t >> 6, lane = t & 63;
  int n = blockIdx.x * 64 + lane;
  int idx = nb[n * 3 + j];
  const float4* row = (const float4*)(rgbT + (size_t)idx * 128);
  for (int c4 = 0; c4 < 32; ++c4) {
    float4 v = row[c4];
    int cb = j * 128 + c4 * 4;
    xcat[(size_t)(cb + 0) * NP + n] = v.x;
    xcat[(size_t)(cb + 1) * NP + n] = v.y;
    xcat[(size_t)(cb + 2) * NP + n] = v.z;
    xcat[(size_t)(cb + 3) * NP + n] = v.w;
  }
}

// ---------------- max over 3 neighbors -> x2 rows 128..255
__global__ __launch_bounds__(256) void k_max3(const float* __restrict__ xcat,
                                              float* __restrict__ x2) {
  int idx = blockIdx.x * 256 + threadIdx.x;   // 128*NP threads
  int c = idx >> 14, n = idx & 16383;
  float a = xcat[(size_t)c * NP + n];
  float b = xcat[(size_t)(128 + c) * NP + n];
  float d = xcat[(size_t)(256 + c) * NP + n];
  x2[(size_t)(128 + c) * NP + n] = fmaxf(a, fmaxf(b, d));
}

// ---------------- generic fp32 GEMM: Y[o,n] = act(bn(sum_c W[o,c] X[c,n] + bias[o]))
// 128x128 tile, 8x8 micro, K-chunk 16
template <bool BN, bool RELU>
__global__ __launch_bounds__(256) void k_gemm(const float* __restrict__ W,
                                              const float* __restrict__ bias,
                                              const float* __restrict__ bn,
                                              const float* __restrict__ X,
                                              float* __restrict__ Y, int O, int C) {
  __shared__ float Xs[16][128];
  __shared__ float Ws[16][132];         // +4 pad: conflict-free transposed writes
  __shared__ float scs[128], shs[128];
  int t = threadIdx.x;
  int n0 = blockIdx.x * 128, o0 = blockIdx.y * 128;
  if (t < 128) {
    int o = o0 + t;
    float sc = 1.f, sh = 0.f;
    if (o < O) {
      float b = bias[o];
      if (BN) {
        float g = bn[o], be = bn[O + o], m = bn[2 * O + o], v = bn[3 * O + o];
        float inv = g * rsqrtf(v + 1e-5f);
        sc = inv; sh = (b - m) * inv + be;
      } else { sh = b; }
    }
    scs[t] = sc; shs[t] = sh;
  }
  float acc[8][8];
#pragma unroll
  for (int a = 0; a < 8; ++a)
#pragma unroll
    for (int b = 0; b < 8; ++b) acc[a][b] = 0.f;
  int tn = t & 15, tc = t >> 4;
  for (int c0 = 0; c0 < C; c0 += 16) {
    __syncthreads();
#pragma unroll
    for (int e = 0; e < 2; ++e) {       // X tile 16k x 128n
      int idx = t + e * 256;
      int k = idx >> 5, n4 = idx & 31;
      float4 v = *(const float4*)(X + (size_t)(c0 + k) * NP + n0 + n4 * 4);
      *(float4*)&Xs[k][n4 * 4] = v;
    }
#pragma unroll
    for (int e = 0; e < 2; ++e) {       // W tile 128o x 16k, transposed into [k][o]
      int idx = t + e * 256;
      int o = idx >> 2, k4 = (idx & 3) * 4;
      float4 v = make_float4(0.f, 0.f, 0.f, 0.f);
      if (o0 + o < O) v = *(const float4*)(W + (size_t)(o0 + o) * C + c0 + k4);
      Ws[k4 + 0][o] = v.x; Ws[k4 + 1][o] = v.y;
      Ws[k4 + 2][o] = v.z; Ws[k4 + 3][o] = v.w;
    }
    __syncthreads();
#pragma unroll
    for (int k = 0; k < 16; ++k) {
      float xa[8], wa[8];
      *(float4*)&xa[0] = *(const float4*)&Xs[k][tn * 8];
      *(float4*)&xa[4] = *(const float4*)&Xs[k][tn * 8 + 4];
      *(float4*)&wa[0] = *(const float4*)&Ws[k][tc * 8];
      *(float4*)&wa[4] = *(const float4*)&Ws[k][tc * 8 + 4];
#pragma unroll
      for (int a = 0; a < 8; ++a)
#pragma unroll
        for (int b = 0; b < 8; ++b) acc[a][b] = fmaf(wa[a], xa[b], acc[a][b]);
    }
  }
#pragma unroll
  for (int a = 0; a < 8; ++a) {
    int o = o0 + tc * 8 + a;
    if (o < O) {
      float sc = scs[tc * 8 + a], sh = shs[tc * 8 + a];
      float r[8];
#pragma unroll
      for (int b = 0; b < 8; ++b) {
        float v = acc[a][b] * sc + sh;
        if (RELU) v = fmaxf(v, 0.f);
        r[b] = v;
      }
      float* yp = Y + (size_t)o * NP + n0 + tn * 8;
      *(float4*)yp = *(float4*)&r[0];
      *(float4*)(yp + 4) = *(float4*)&r[4];
    }
  }
}

// ---------------- score head: sigmoid(sh2_w . s + b)
__global__ __launch_bounds__(256) void k_score(const float* __restrict__ S,
                                               const float* __restrict__ w,
                                               const float* __restrict__ b,
                                               float* __restrict__ out) {
  int n = blockIdx.x * 256 + threadIdx.x;
  float acc = b[0];
  for (int c = 0; c < 128; ++c) acc = fmaf(w[c], S[(size_t)c * NP + n], acc);
  out[n] = 1.f / (1.f + expf(-acc));
}

// ---------------- L2-normalize fp columns, write transposed (NP, 128)
__global__ __launch_bounds__(256) void k_norm(const float* __restrict__ FP,
                                              float* __restrict__ out) {
  __shared__ float tile[128][65];
  __shared__ float part[4][64];
  __shared__ float inv[64];
  int t = threadIdx.x;
  int n0 = blockIdx.x * 64;
  for (int e = 0; e < 32; ++e) {
    int idx = t + e * 256;
    int c = idx >> 6, j = idx & 63;
    tile[c][j] = FP[(size_t)c * NP + n0 + j];
  }
  __syncthreads();
  int g = t >> 6, j = t & 63;
  float s = 0.f;
  for (int c = g * 32; c < g * 32 + 32; ++c) { float v = tile[c][j]; s = fmaf(v, v, s); }
  part[g][j] = s;
  __syncthreads();
  if (t < 64) {
    float nrm = sqrtf(part[0][t] + part[1][t] + part[2][t] + part[3][t]);
    inv[t] = 1.f / fmaxf(nrm, 1e-12f);
  }
  __syncthreads();
  for (int e = 0; e < 32; ++e) {
    int idx = t + e * 256;
    int jj = idx >> 7, c = idx & 127;
    out[(size_t)(n0 + jj) * 128 + c] = tile[c][jj] * inv[jj];
  }
}

// ---------------- float4 copy
__global__ __launch_bounds__(256) void k_copy4(const float4* __restrict__ src,
                                               float4* __restrict__ dst, int n4) {
  int i = blockIdx.x * 256 + threadIdx.x;
  if (i < n4) dst[i] = src[i];
}

extern "C" void kernel_launch(void* const* d_in, const int* in_sizes, int n_in,
                              void* d_out, int out_size, void* d_ws, size_t ws_size,
                              hipStream_t stream) {
  const float* pcd_xyz = (const float*)d_in[0];
  const float* rgb_xyz = (const float*)d_in[1];
  const float* pcd_f   = (const float*)d_in[2];
  const float* rgb_f   = (const float*)d_in[3];
  const float* cc1_w = (const float*)d_in[4];  const float* cc1_b = (const float*)d_in[5];
  const float* cc_bn = (const float*)d_in[6];
  const float* cc2_w = (const float*)d_in[7];  const float* cc2_b = (const float*)d_in[8];
  const float* co1_w = (const float*)d_in[9];  const float* co1_b = (const float*)d_in[10];
  const float* co_bn = (const float*)d_in[11];
  const float* co2_w = (const float*)d_in[12]; const float* co2_b = (const float*)d_in[13];
  const float* dh1_w = (const float*)d_in[14]; const float* dh1_b = (const float*)d_in[15];
  const float* dh1_bn = (const float*)d_in[16];
  const float* dh2_w = (const float*)d_in[17]; const float* dh2_b = (const float*)d_in[18];
  const float* dh2_bn = (const float*)d_in[19];
  const float* dh3_w = (const float*)d_in[20]; const float* dh3_b = (const float*)d_in[21];
  const float* sh1_w = (const float*)d_in[22]; const float* sh1_b = (const float*)d_in[23];
  const float* sh_bn = (const float*)d_in[24];
  const float* sh2_w = (const float*)d_in[25]; const float* sh2_b = (const float*)d_in[26];

  float* ws = (float*)d_ws;
  float* out = (float*)d_out;

  // workspace layout (floats); ~90.4 MB total with aliasing
  float* rgbT = ws;                                  // 8193*128 = 1,048,704
  int*   nb   = (int*)(ws + 1048704);                // 49,152 ints
  float* bufA = ws + 1097856;                        // 6,291,456 : x_cat; later h3/h4
  float* bufB = ws + 7389312;                        // 6,291,456 : nn partials; h1; h2; s
  float* x2   = ws + 13680768;                       // 4,194,304
  float* full = ws + 17875072;                       // 2,621,440
  float* fp   = ws + 20496512;                       // 2,097,152
  float* h3 = bufA;
  float* h4 = bufA + 2621440;
  // nn partials alias bufB (dead until cc1 output): 393216 floats + 393216 ints
  float* pd = bufB;
  int*   pi = (int*)(bufB + 393216);

  k_transpose<<<128, 256, 0, stream>>>(rgb_f, rgbT);
  k_nn_part<<<dim3(256, 8), 256, 0, stream>>>(pcd_xyz, rgb_xyz, pd, pi);
  k_nn_merge<<<64, 256, 0, stream>>>(pd, pi, nb);
  k_gather<<<256, 192, 0, stream>>>(rgbT, nb, bufA);                 // x_cat
  k_max3<<<8192, 256, 0, stream>>>(bufA, x2);                        // x2 rows 128..255
  k_copy4<<<512, 256, 0, stream>>>((const float4*)pcd_f, (float4*)full, 131072); // full rows 0..31

  k_gemm<true, true><<<dim3(128, 3), 256, 0, stream>>>(cc1_w, cc1_b, cc_bn, bufA, bufB, 384, 384);
  k_gemm<false, false><<<dim3(128, 1), 256, 0, stream>>>(cc2_w, cc2_b, nullptr, bufB, x2, 128, 384);
  k_gemm<true, true><<<dim3(128, 2), 256, 0, stream>>>(co1_w, co1_b, co_bn, x2, bufB, 256, 256);
  k_gemm<false, false><<<dim3(128, 1), 256, 0, stream>>>(co2_w, co2_b, nullptr, bufB, full + 32 * NP, 128, 256);
  k_gemm<true, true><<<dim3(128, 2), 256, 0, stream>>>(dh1_w, dh1_b, dh1_bn, full, h3, 160, 160);
  k_gemm<true, true><<<dim3(128, 2), 256, 0, stream>>>(dh2_w, dh2_b, dh2_bn, h3, h4, 160, 160);
  k_gemm<false, false><<<dim3(128, 1), 256, 0, stream>>>(dh3_w, dh3_b, nullptr, h4, fp, 128, 160);
  k_gemm<true, true><<<dim3(128, 1), 256, 0, stream>>>(sh1_w, sh1_b, sh_bn, fp, bufB, 128, 128);

  k_score<<<64, 256, 0, stream>>>(bufB, sh2_w, sh2_b, out + 49152);
  k_norm<<<256, 256, 0, stream>>>(fp, out + 65536);
  k_copy4<<<48, 256, 0, stream>>>((const float4*)pcd_xyz, (float4*)out, 12288);
}

// Round 3
// 280.439 us; speedup vs baseline: 2.2915x; 1.8974x over previous
//
#include <hip/hip_runtime.h>
#include <math.h>

#define NP 16384
#define NR 8192

typedef __attribute__((ext_vector_type(8))) short short8;
typedef __attribute__((ext_vector_type(4))) float f32x4;

__device__ inline unsigned short f2b(float f) {
  unsigned int x = __float_as_uint(f);
  return (unsigned short)((x + 0x7FFFu + ((x >> 16) & 1u)) >> 16);  // RNE
}
__device__ inline float blo(unsigned int u) { return __uint_as_float(u << 16); }
__device__ inline float bhi(unsigned int u) { return __uint_as_float(u & 0xffff0000u); }

// ---------------- convert 8 weight matrices f32 -> bf16 (one kernel)
__global__ __launch_bounds__(256) void k_wconv(const float* __restrict__ s0, const float* __restrict__ s1,
                                               const float* __restrict__ s2, const float* __restrict__ s3,
                                               const float* __restrict__ s4, const float* __restrict__ s5,
                                               const float* __restrict__ s6, const float* __restrict__ s7,
                                               unsigned short* __restrict__ dst) {
  const int sizes[8] = {147456, 49152, 65536, 32768, 25600, 25600, 20480, 16384};
  const int offs[8]  = {0, 147456, 196608, 262144, 294912, 320512, 346112, 366592};
  const float* srcs[8] = {s0, s1, s2, s3, s4, s5, s6, s7};
  int m = blockIdx.y;
  int i = (blockIdx.x * 256 + threadIdx.x) * 8;
  if (i >= sizes[m]) return;
  const float4* sp = (const float4*)(srcs[m] + i);
  float4 a = sp[0], b = sp[1];
  uint4 o;
  o.x = f2b(a.x) | ((unsigned int)f2b(a.y) << 16);
  o.y = f2b(a.z) | ((unsigned int)f2b(a.w) << 16);
  o.z = f2b(b.x) | ((unsigned int)f2b(b.y) << 16);
  o.w = f2b(b.z) | ((unsigned int)f2b(b.w) << 16);
  *(uint4*)(dst + offs[m] + i) = o;
}

// ---------------- transpose rgb_features (128, NR) f32 -> rgbTb (NR+1, 128) bf16
__global__ __launch_bounds__(256) void k_transpose_rgb(const float* __restrict__ rf,
                                                       unsigned short* __restrict__ rgbTb) {
  __shared__ float tile[128][65];
  int t = threadIdx.x;
  int r0 = blockIdx.x * 64;
  for (int e = 0; e < 32; ++e) {
    int idx = t + e * 256;
    int c = idx >> 6, rl = idx & 63;
    tile[c][rl] = rf[c * NR + r0 + rl];
  }
  __syncthreads();
  for (int e = 0; e < 32; ++e) {
    int idx = t + e * 256;
    int rl = idx >> 7, c = idx & 127;
    rgbTb[(size_t)(r0 + rl) * 128 + c] = f2b(tile[c][rl]);
  }
  if (blockIdx.x == 0 && t < 128) rgbTb[(size_t)NR * 128 + t] = 0;
}

// ---------------- transpose pcd_features (32, NP) f32 -> full[n][0..31] bf16 (ld 160)
__global__ __launch_bounds__(256) void k_transpose_pcd(const float* __restrict__ pf,
                                                       unsigned short* __restrict__ full) {
  __shared__ float tile[32][65];
  int t = threadIdx.x;
  int n0 = blockIdx.x * 64;
  for (int e = 0; e < 8; ++e) {
    int idx = t + e * 256;
    int c = idx >> 6, nl = idx & 63;
    tile[c][nl] = pf[c * NP + n0 + nl];
  }
  __syncthreads();
  for (int e = 0; e < 8; ++e) {
    int idx = t + e * 256;
    int nl = idx >> 5, c = idx & 31;
    full[(size_t)(n0 + nl) * 160 + c] = f2b(tile[c][nl]);
  }
}

// ---------------- three_nn partials (unchanged from R1)
__global__ __launch_bounds__(256) void k_nn_part(const float* __restrict__ pxyz,
                                                 const float* __restrict__ rxyz,
                                                 float* __restrict__ pd,
                                                 int* __restrict__ pi) {
  __shared__ float4 pts[1024];
  __shared__ float msd[4][3][64];
  __shared__ int   mid[4][3][64];
  int t = threadIdx.x;
  int g = blockIdx.x, s = blockIdx.y;
  int lane = t & 63, w = t >> 6;
  int rbase = s * 1024;
#pragma unroll
  for (int e = 0; e < 4; ++e) {
    int q = t + e * 256;
    int ri = (rbase + q) * 3;
    pts[q] = make_float4(rxyz[ri], rxyz[ri + 1], rxyz[ri + 2], 0.f);
  }
  int n = g * 64 + lane;
  float px = pxyz[n * 3], py = pxyz[n * 3 + 1], pz = pxyz[n * 3 + 2];
  __syncthreads();
  float s0 = 3.4e38f, s1 = 3.4e38f, s2 = 3.4e38f;
  int i0 = 0, i1 = 0, i2 = 0;
  int base = w * 256;
#pragma unroll 4
  for (int loc = 0; loc < 256; ++loc) {
    float4 r = pts[base + loc];
    float dx = px - r.x, dy = py - r.y, dz = pz - r.z;
    float d2 = fmaf(dx, dx, fmaf(dy, dy, dz * dz));
    if (d2 < s2) {
      int i = rbase + base + loc;
      if (d2 < s1) {
        s2 = s1; i2 = i1;
        if (d2 < s0) { s1 = s0; i1 = i0; s0 = d2; i0 = i; }
        else         { s1 = d2; i1 = i; }
      } else { s2 = d2; i2 = i; }
    }
  }
  msd[w][0][lane] = s0; msd[w][1][lane] = s1; msd[w][2][lane] = s2;
  mid[w][0][lane] = i0; mid[w][1][lane] = i1; mid[w][2][lane] = i2;
  __syncthreads();
  if (t < 64) {
    s0 = msd[0][0][t]; s1 = msd[0][1][t]; s2 = msd[0][2][t];
    i0 = mid[0][0][t]; i1 = mid[0][1][t]; i2 = mid[0][2][t];
    for (int ww = 1; ww < 4; ++ww) {
      for (int q = 0; q < 3; ++q) {
        float d2 = msd[ww][q][t]; int i = mid[ww][q][t];
        if (d2 < s2) {
          if (d2 < s1) {
            s2 = s1; i2 = i1;
            if (d2 < s0) { s1 = s0; i1 = i0; s0 = d2; i0 = i; }
            else         { s1 = d2; i1 = i; }
          } else { s2 = d2; i2 = i; }
        }
      }
    }
    int off = ((g * 8 + s) * 64 + t) * 3;
    pd[off + 0] = s0; pd[off + 1] = s1; pd[off + 2] = s2;
    pi[off + 0] = i0; pi[off + 1] = i1; pi[off + 2] = i2;
  }
}

__global__ __launch_bounds__(256) void k_nn_merge(const float* __restrict__ pd,
                                                  const int* __restrict__ pi,
                                                  int* __restrict__ nb) {
  int n = blockIdx.x * 256 + threadIdx.x;
  int g = n >> 6, l = n & 63;
  float s0 = 3.4e38f, s1 = 3.4e38f, s2 = 3.4e38f;
  int i0 = 0, i1 = 0, i2 = 0;
  for (int s = 0; s < 8; ++s) {
    int off = ((g * 8 + s) * 64 + l) * 3;
#pragma unroll
    for (int q = 0; q < 3; ++q) {
      float d2 = pd[off + q]; int i = pi[off + q];
      if (d2 < s2) {
        if (d2 < s1) {
          s2 = s1; i2 = i1;
          if (d2 < s0) { s1 = s0; i1 = i0; s0 = d2; i0 = i; }
          else         { s1 = d2; i1 = i; }
        } else { s2 = d2; i2 = i; }
      }
    }
  }
  const float R2 = 0.075f * 0.075f;
  nb[n * 3 + 0] = (s0 > R2) ? NR : i0;
  nb[n * 3 + 1] = (s1 > R2) ? NR : i1;
  nb[n * 3 + 2] = (s2 > R2) ? NR : i2;
}

// ---------------- gather 3 neighbor rows -> xcat row (384 bf16) + elementwise max -> x2[n][128..255]
__global__ __launch_bounds__(256) void k_gather_max(const unsigned short* __restrict__ rgbTb,
                                                    const int* __restrict__ nb,
                                                    unsigned short* __restrict__ xcat,
                                                    unsigned short* __restrict__ x2) {
  int t = threadIdx.x, lane = t & 63, w = t >> 6;
  int n = blockIdx.x * 4 + w;
  int j0 = nb[n * 3 + 0], j1 = nb[n * 3 + 1], j2 = nb[n * 3 + 2];
  unsigned int a = ((const unsigned int*)(rgbTb + (size_t)j0 * 128))[lane];
  unsigned int b = ((const unsigned int*)(rgbTb + (size_t)j1 * 128))[lane];
  unsigned int c = ((const unsigned int*)(rgbTb + (size_t)j2 * 128))[lane];
  unsigned int* xr = (unsigned int*)(xcat + (size_t)n * 384);
  xr[lane] = a; xr[64 + lane] = b; xr[128 + lane] = c;
  float ml = fmaxf(blo(a), fmaxf(blo(b), blo(c)));
  float mh = fmaxf(bhi(a), fmaxf(bhi(b), bhi(c)));
  unsigned int m = (__float_as_uint(mh) & 0xffff0000u) | (__float_as_uint(ml) >> 16);
  ((unsigned int*)(x2 + (size_t)n * 256 + 128))[lane] = m;
}

// ---------------- bf16 MFMA GEMM: Y[n][o] = act(sc[o]*(W X)[o][n] + sh[o])
// W (O,C) bf16 row-major; X (NP,C) bf16 row-major; Y rows stride ldY (bf16), col block at o0..
// 128n x 128o tile, 4 waves (2x2), 16x16x32 mfma, 4x4 acc tiles/wave.
template <bool BN, bool RELU>
__global__ __launch_bounds__(256) void k_bgemm(const unsigned short* __restrict__ Wb,
                                               const float* __restrict__ bias,
                                               const float* __restrict__ bnp,
                                               const unsigned short* __restrict__ X,
                                               unsigned short* __restrict__ Y,
                                               int O, int C, int ldY) {
  __shared__ unsigned short Xs[128 * 40];  // 32k per row + 8 pad (2-way banks = free)
  __shared__ unsigned short Wl[128 * 40];
  __shared__ float scsh[256];
  int t = threadIdx.x;
  int lane = t & 63, w = t >> 6;
  int wn = w & 1, wm = w >> 1;
  int q = lane >> 4, l15 = lane & 15;
  int n0 = blockIdx.x * 128, o0 = blockIdx.y * 128;
  if (t < 128) {
    int o = o0 + t;
    float sc = 0.f, sh = 0.f;
    if (o < O) {
      float b = bias[o];
      if (BN) {
        float g = bnp[o], be = bnp[O + o], m = bnp[2 * O + o], v = bnp[3 * O + o];
        float inv = g * rsqrtf(v + 1e-5f);
        sc = inv; sh = (b - m) * inv + be;
      } else { sc = 1.f; sh = b; }
    }
    scsh[t] = sc; scsh[128 + t] = sh;
  }
  f32x4 acc[4][4] = {};
  for (int c0 = 0; c0 < C; c0 += 32) {
    __syncthreads();
#pragma unroll
    for (int e = 0; e < 2; ++e) {
      int idx = e * 256 + t;
      int row = idx >> 2, kb = idx & 3;
      uint4 xv = *(const uint4*)(X + (size_t)(n0 + row) * C + c0 + kb * 8);
      *(uint4*)&Xs[row * 40 + kb * 8] = xv;
      int go = o0 + row; if (go >= O) go = O - 1;       // clamp; masked at store
      uint4 wv = *(const uint4*)(Wb + (size_t)go * C + c0 + kb * 8);
      *(uint4*)&Wl[row * 40 + kb * 8] = wv;
    }
    __syncthreads();
    short8 af[4], bf[4];
#pragma unroll
    for (int a = 0; a < 4; ++a)
      af[a] = *(const short8*)&Wl[(wm * 64 + a * 16 + l15) * 40 + q * 8];
#pragma unroll
    for (int b = 0; b < 4; ++b)
      bf[b] = *(const short8*)&Xs[(wn * 64 + b * 16 + l15) * 40 + q * 8];
#pragma unroll
    for (int a = 0; a < 4; ++a)
#pragma unroll
      for (int b = 0; b < 4; ++b)
        acc[a][b] = __builtin_amdgcn_mfma_f32_16x16x32_bf16(af[a], bf[b], acc[a][b], 0, 0, 0);
  }
  // epilogue: per-wave LDS transpose (64n x 16o f32, rows padded to 20), then bf16 (N,C) store
  __syncthreads();
  float* lt = (w < 2) ? ((float*)Xs + w * 1280) : ((float*)Wl + (w - 2) * 1280);
#pragma unroll
  for (int a = 0; a < 4; ++a) {
    int oTile = wm * 64 + a * 16;
    if (o0 + oTile >= O) continue;
    float scr[4], shr[4];
#pragma unroll
    for (int r = 0; r < 4; ++r) {
      scr[r] = scsh[oTile + q * 4 + r];
      shr[r] = scsh[128 + oTile + q * 4 + r];
    }
#pragma unroll
    for (int b = 0; b < 4; ++b) {
      int nl = b * 16 + l15;
      f32x4 v;
#pragma unroll
      for (int r = 0; r < 4; ++r) {
        float x = acc[a][b][r] * scr[r] + shr[r];
        if (RELU) x = fmaxf(x, 0.f);
        v[r] = x;
      }
      *(f32x4*)&lt[nl * 20 + q * 4] = v;     // wave-local; compiler inserts lgkmcnt
    }
#pragma unroll
    for (int g = 0; g < 4; ++g) {
      int nl = g * 16 + (lane >> 2);
      int ob = (lane & 3) * 4;
      f32x4 v = *(const f32x4*)&lt[nl * 20 + ob];
      ushort4 u;
      u.x = f2b(v[0]); u.y = f2b(v[1]); u.z = f2b(v[2]); u.w = f2b(v[3]);
      *(ushort4*)(Y + (size_t)(n0 + wn * 64 + nl) * ldY + o0 + oTile + ob) = u;
    }
  }
}

// ---------------- score head: sigmoid(sh2_w . s_row + b); s rows bf16 (NP,128)
__global__ __launch_bounds__(256) void k_score_b(const unsigned short* __restrict__ S,
                                                 const float* __restrict__ wv,
                                                 const float* __restrict__ bv,
                                                 float* __restrict__ out) {
  int t = threadIdx.x, lane = t & 63, w = t >> 6;
  int row = blockIdx.x * 16 + w * 4 + (lane >> 4);
  int col8 = (lane & 15) * 8;
  uint4 raw = *(const uint4*)(S + (size_t)row * 128 + col8);
  float4 w0 = *(const float4*)(wv + col8);
  float4 w1 = *(const float4*)(wv + col8 + 4);
  float acc = blo(raw.x) * w0.x + bhi(raw.x) * w0.y + blo(raw.y) * w0.z + bhi(raw.y) * w0.w +
              blo(raw.z) * w1.x + bhi(raw.z) * w1.y + blo(raw.w) * w1.z + bhi(raw.w) * w1.w;
  acc += __shfl_xor(acc, 1); acc += __shfl_xor(acc, 2);
  acc += __shfl_xor(acc, 4); acc += __shfl_xor(acc, 8);
  if ((lane & 15) == 0) out[row] = 1.f / (1.f + expf(-(acc + bv[0])));
}

// ---------------- L2-normalize fp rows (NP,128) bf16 -> out f32 (NP,128)
__global__ __launch_bounds__(256) void k_norm_b(const unsigned short* __restrict__ FP,
                                                float* __restrict__ out) {
  int t = threadIdx.x, lane = t & 63, w = t >> 6;
  int row = blockIdx.x * 16 + w * 4 + (lane >> 4);
  int col8 = (lane & 15) * 8;
  uint4 raw = *(const uint4*)(FP + (size_t)row * 128 + col8);
  float v[8] = {blo(raw.x), bhi(raw.x), blo(raw.y), bhi(raw.y),
                blo(raw.z), bhi(raw.z), blo(raw.w), bhi(raw.w)};
  float s = 0.f;
#pragma unroll
  for (int i = 0; i < 8; ++i) s = fmaf(v[i], v[i], s);
  s += __shfl_xor(s, 1); s += __shfl_xor(s, 2);
  s += __shfl_xor(s, 4); s += __shfl_xor(s, 8);
  float inv = 1.f / fmaxf(sqrtf(s), 1e-12f);
  float4 o0 = make_float4(v[0] * inv, v[1] * inv, v[2] * inv, v[3] * inv);
  float4 o1 = make_float4(v[4] * inv, v[5] * inv, v[6] * inv, v[7] * inv);
  float* op = out + (size_t)row * 128 + col8;
  *(float4*)op = o0;
  *(float4*)(op + 4) = o1;
}

// ---------------- float4 copy
__global__ __launch_bounds__(256) void k_copy4(const float4* __restrict__ src,
                                               float4* __restrict__ dst, int n4) {
  int i = blockIdx.x * 256 + threadIdx.x;
  if (i < n4) dst[i] = src[i];
}

extern "C" void kernel_launch(void* const* d_in, const int* in_sizes, int n_in,
                              void* d_out, int out_size, void* d_ws, size_t ws_size,
                              hipStream_t stream) {
  const float* pcd_xyz = (const float*)d_in[0];
  const float* rgb_xyz = (const float*)d_in[1];
  const float* pcd_f   = (const float*)d_in[2];
  const float* rgb_f   = (const float*)d_in[3];
  const float* cc1_w = (const float*)d_in[4];  const float* cc1_b = (const float*)d_in[5];
  const float* cc_bn = (const float*)d_in[6];
  const float* cc2_w = (const float*)d_in[7];  const float* cc2_b = (const float*)d_in[8];
  const float* co1_w = (const float*)d_in[9];  const float* co1_b = (const float*)d_in[10];
  const float* co_bn = (const float*)d_in[11];
  const float* co2_w = (const float*)d_in[12]; const float* co2_b = (const float*)d_in[13];
  const float* dh1_w = (const float*)d_in[14]; const float* dh1_b = (const float*)d_in[15];
  const float* dh1_bn = (const float*)d_in[16];
  const float* dh2_w = (const float*)d_in[17]; const float* dh2_b = (const float*)d_in[18];
  const float* dh2_bn = (const float*)d_in[19];
  const float* dh3_w = (const float*)d_in[20]; const float* dh3_b = (const float*)d_in[21];
  const float* sh1_w = (const float*)d_in[22]; const float* sh1_b = (const float*)d_in[23];
  const float* sh_bn = (const float*)d_in[24];
  const float* sh2_w = (const float*)d_in[25]; const float* sh2_b = (const float*)d_in[26];

  char* ws = (char*)d_ws;
  float* out = (float*)d_out;

  // byte-offset workspace layout (~78 MB)
  unsigned short* wb    = (unsigned short*)(ws);              // 382,976 bf16 = 766 KB
  unsigned short* rgbTb = (unsigned short*)(ws + 0x100000);   // (NR+1)*128 = 2.1 MB
  int*   nb  = (int*)(ws + 0x400000);                         // 49,152 ints
  float* pd  = (float*)(ws + 0x500000);                       // 393,216 f32
  int*   pi  = (int*)(ws + 0x680000);                         // 393,216 ints
  unsigned short* xcat = (unsigned short*)(ws + 0x800000);    // (NP,384) 12.6 MB
  unsigned short* h1   = (unsigned short*)(ws + 0x1400000);   // (NP,384)
  unsigned short* x2   = (unsigned short*)(ws + 0x2000000);   // (NP,256)
  unsigned short* h2   = (unsigned short*)(ws + 0x2800000);   // (NP,256)
  unsigned short* full = (unsigned short*)(ws + 0x3000000);   // (NP,160)
  unsigned short* h3   = (unsigned short*)(ws + 0x3600000);   // (NP,160)
  unsigned short* h4   = (unsigned short*)(ws + 0x3C00000);   // (NP,160)
  unsigned short* fp   = (unsigned short*)(ws + 0x4200000);   // (NP,128)
  unsigned short* sB   = (unsigned short*)(ws + 0x4600000);   // (NP,128)

  unsigned short* wb_cc1 = wb;
  unsigned short* wb_cc2 = wb + 147456;
  unsigned short* wb_co1 = wb + 196608;
  unsigned short* wb_co2 = wb + 262144;
  unsigned short* wb_dh1 = wb + 294912;
  unsigned short* wb_dh2 = wb + 320512;
  unsigned short* wb_dh3 = wb + 346112;
  unsigned short* wb_sh1 = wb + 366592;

  k_wconv<<<dim3(72, 8), 256, 0, stream>>>(cc1_w, cc2_w, co1_w, co2_w, dh1_w, dh2_w, dh3_w, sh1_w, wb);
  k_transpose_rgb<<<128, 256, 0, stream>>>(rgb_f, rgbTb);
  k_nn_part<<<dim3(256, 8), 256, 0, stream>>>(pcd_xyz, rgb_xyz, pd, pi);
  k_nn_merge<<<64, 256, 0, stream>>>(pd, pi, nb);
  k_gather_max<<<4096, 256, 0, stream>>>(rgbTb, nb, xcat, x2);
  k_transpose_pcd<<<256, 256, 0, stream>>>(pcd_f, full);

  k_bgemm<true, true><<<dim3(128, 3), 256, 0, stream>>>(wb_cc1, cc1_b, cc_bn, xcat, h1, 384, 384, 384);
  k_bgemm<false, false><<<dim3(128, 1), 256, 0, stream>>>(wb_cc2, cc2_b, nullptr, h1, x2, 128, 384, 256);
  k_bgemm<true, true><<<dim3(128, 2), 256, 0, stream>>>(wb_co1, co1_b, co_bn, x2, h2, 256, 256, 256);
  k_bgemm<false, false><<<dim3(128, 1), 256, 0, stream>>>(wb_co2, co2_b, nullptr, h2, full + 32, 128, 256, 160);
  k_bgemm<true, true><<<dim3(128, 2), 256, 0, stream>>>(wb_dh1, dh1_b, dh1_bn, full, h3, 160, 160, 160);
  k_bgemm<true, true><<<dim3(128, 2), 256, 0, stream>>>(wb_dh2, dh2_b, dh2_bn, h3, h4, 160, 160, 160);
  k_bgemm<false, false><<<dim3(128, 1), 256, 0, stream>>>(wb_dh3, dh3_b, nullptr, h4, fp, 128, 160, 128);
  k_bgemm<true, true><<<dim3(128, 1), 256, 0, stream>>>(wb_sh1, sh1_b, sh_bn, fp, sB, 128, 128, 128);

  k_score_b<<<1024, 256, 0, stream>>>(sB, sh2_w, sh2_b, out + 49152);
  k_norm_b<<<1024, 256, 0, stream>>>(fp, out + 65536);
  k_copy4<<<48, 256, 0, stream>>>((const float4*)pcd_xyz, (float4*)out, 12288);
}